// Round 1
// baseline (10.902 us; speedup 1.0000x reference)
//
#include <hip/hip_runtime.h>

// CZ ring on 12 wires is a product of diagonal gates:
//   U[s,s] = (-1)^( sum_{j=0}^{11} bit_j(s) * bit_{(j+1)%12}(s) )
// so reference(x) = D * x with D a +/-1 diagonal. Pure elementwise sign flip.
//
// x is [4096, 1024] row-major float32 -> 1024 floats (256 float4) per row.

__global__ __launch_bounds__(256) void czring_sign_kernel(
    const float4* __restrict__ x, float4* __restrict__ out) {
    unsigned g = blockIdx.x * blockDim.x + threadIdx.x;   // 0 .. 2^20-1
    unsigned row = g >> 8;                                // 256 float4 per row
    unsigned rot = ((row << 1) | (row >> 11)) & 0xFFFu;   // cyclic left rot, 12 bits
    int parity = __popc(row & rot) & 1;
    float s = parity ? -1.0f : 1.0f;
    float4 v = x[g];
    v.x *= s; v.y *= s; v.z *= s; v.w *= s;
    out[g] = v;
}

extern "C" void kernel_launch(void* const* d_in, const int* in_sizes, int n_in,
                              void* d_out, int out_size, void* d_ws, size_t ws_size,
                              hipStream_t stream) {
    const float4* x = (const float4*)d_in[0];
    float4* out = (float4*)d_out;
    // 4096 * 1024 floats = 2^20 float4s
    const int total_vec4 = (4096 * 1024) / 4;
    const int block = 256;
    const int grid = total_vec4 / block;  // 4096
    czring_sign_kernel<<<grid, block, 0, stream>>>(x, out);
}